// Round 5
// baseline (106.044 us; speedup 1.0000x reference)
//
#include <hip/hip_runtime.h>
#include <cstddef>

typedef _Float16 f16_t;
typedef _Float16 f16x8 __attribute__((ext_vector_type(8)));
typedef float    f32x4  __attribute__((ext_vector_type(4)));
typedef float    f32x16 __attribute__((ext_vector_type(16)));

static constexpr int NN = 64;    // nodes
static constexpr int FF = 4;     // features
static constexpr int HH = 256;   // hidden

// ---- workspace layout (bytes) ----
// W2p    @ 0       : 131072   (W_msg2 packed 32x32x16 B-frags, f16)
// W1op   @ 131072  : 147456   (W_out1 padded/remapped 16x16x32, f16)
// W2op   @ 278528  : 131072   (W_out2 packed 16x16x32, f16)
// innode @ 409600  : 4718592  ([agg(256) | x(4) | pad(28)] f16, 8192 rows)
// Vp     @ 5128192 : 4194304  (V = x @ W1[4:8], f16 [128][64][256])

// ------------------------------------------------------------------
// 16x16x32 B-frag pack: lane holds B[k=ks*32+(lane>>4)*8+j][col=nt*16+(lane&15)]
// ------------------------------------------------------------------
__device__ inline void pack_frag16(const float* __restrict__ src, f16_t* __restrict__ dst,
                                   int fid, int ksteps, int mode)
{
    if (fid >= ksteps * 1024) return;
    int lane = fid & 63;
    int nt   = (fid >> 6) & 15;
    int ks   = fid >> 10;
    int col  = nt * 16 + (lane & 15);
    int kb   = ks * 32 + (lane >> 4) * 8;
    #pragma unroll
    for (int j = 0; j < 8; ++j) {
        int k = kb + j;
        float v;
        if (mode == 0) {
            v = src[k * 256 + col];
        } else {
            if (k < 256)      v = src[(4 + k) * 256 + col];
            else if (k < 260) v = src[(k - 256) * 256 + col];
            else              v = 0.f;
        }
        dst[(size_t)fid * 8 + j] = (f16_t)v;
    }
}

// ------------------------------------------------------------------
// 32x32x16 B-frag pack: lane holds B[k=ks*16+(lane>>5)*8+j][col=nt*32+(lane&31)]
// fid = (ks*8 + nt)*64 + lane, ks in [0,16), nt in [0,8)
// ------------------------------------------------------------------
__device__ inline void pack_frag32(const float* __restrict__ src, f16_t* __restrict__ dst,
                                   int fid)
{
    int lane = fid & 63;
    int nt   = (fid >> 6) & 7;
    int ks   = fid >> 9;
    int col  = nt * 32 + (lane & 31);
    int kb   = ks * 16 + (lane >> 5) * 8;
    #pragma unroll
    for (int j = 0; j < 8; ++j)
        dst[(size_t)fid * 8 + j] = (f16_t)src[(kb + j) * 256 + col];
}

// ------------------------------------------------------------------
// Fused prep: weight packs + V precompute.
// blocks [0,32): W2p(32x32)  [32,68): W1op  [68,100): W2op  [100,1124): Vp
// ------------------------------------------------------------------
__global__ void prep_all(const float* __restrict__ x,
                         const float* __restrict__ W_msg1,
                         const float* __restrict__ W_msg2,
                         const float* __restrict__ W_out1,
                         const float* __restrict__ W_out2,
                         f16_t* __restrict__ W2p, f16_t* __restrict__ W1op,
                         f16_t* __restrict__ W2op, f16_t* __restrict__ Vp)
{
    int bid = blockIdx.x, tid = threadIdx.x;
    if (bid < 32) {
        pack_frag32(W_msg2, W2p, bid * 256 + tid);
    } else if (bid < 68) {
        pack_frag16(W_out1, W1op, (bid - 32) * 256 + tid, 9, 1);
    } else if (bid < 100) {
        pack_frag16(W_out2, W2op, (bid - 68) * 256 + tid, 8, 0);
    } else {
        int gid  = (bid - 100) * 256 + tid;   // 262144
        int rown = gid >> 5;                   // b*64+n
        int h0   = (gid & 31) * 8;
        float4 xv = ((const float4*)x)[rown];
        f16x8 o;
        #pragma unroll
        for (int u = 0; u < 8; ++u) {
            float s = xv.x * W_msg1[4 * HH + h0 + u] + xv.y * W_msg1[5 * HH + h0 + u]
                    + xv.z * W_msg1[6 * HH + h0 + u] + xv.w * W_msg1[7 * HH + h0 + u];
            o[u] = (f16_t)s;
        }
        *(f16x8*)(Vp + (size_t)rown * HH + h0) = o;
    }
}

// ------------------------------------------------------------------
// Edge MLP + aggregation. One block = (batch b, receivers i0,i1).
// h1[r] = relu(U_recv + V_j), packed fp16; LDS [128][256] f16, 5-bit
// slot swizzle (conflict-free, PMC-verified 0 conflicts in R4).
// GEMM: mfma_f32_32x32x16_f16; wave = 2mt x 2nt (grid 2x4) so each
// A-frag ds_read feeds TWO MFMAs -> LDS pipe ~4-6K cyc/round vs MFMA
// 8.2K (was 1:1 at ~10K, co-limiting). B re-read 2x (harmless per R3).
// Self rows zeroed in h1; agg corrected by subtracting relu(b2).
// ------------------------------------------------------------------
__global__ __launch_bounds__(512, 4) void edge_kernel(
    const float* __restrict__ x,      // [128][64][4]
    const float* __restrict__ W1,     // [8][256]
    const float* __restrict__ b1,     // [256]
    const f16_t* __restrict__ Vp,     // [128][64][256]
    const f16_t* __restrict__ W2p,    // packed 32x32
    const float* __restrict__ b2,     // [256]
    f16_t* __restrict__ innode)       // [8192][288]
{
    __shared__ __align__(16) char h1[128 * 512];   // 64 KiB f16, swizzled
    __shared__ __align__(16) f16_t Utab[2][256];

    const int tid  = threadIdx.x;
    const int lane = tid & 63;
    const int w    = tid >> 6;
    const int b    = blockIdx.x >> 5;
    const int pr   = blockIdx.x & 31;
    const int i0   = pr * 2, i1 = i0 + 1;

    // ---- U table: one (recv, h) element per thread ----
    {
        int rs   = tid >> 8;              // 0 -> i0, 1 -> i1
        int h    = tid & 255;
        int node = rs ? i1 : i0;
        const float* xr = x + (b * NN + node) * FF;
        float s = b1[h] + xr[0] * W1[h] + xr[1] * W1[HH + h]
                        + xr[2] * W1[2 * HH + h] + xr[3] * W1[3 * HH + h];
        Utab[rs][h] = (f16_t)s;
    }
    // x + zero-pad tail columns 256..287 of innode
    if (tid < 64) {
        int node = (tid < 32) ? i0 : i1;
        int c = tid & 31;
        float v = (c < 4) ? x[(b * NN + node) * FF + c] : 0.f;
        innode[(size_t)(b * NN + node) * 288 + 256 + c] = (f16_t)v;
    }
    __syncthreads();

    // ---- h1: thread = (row-group rg 0..15, 8 rows) x (8-col block hb) ----
    {
        const int hb = tid & 31;
        const int rg = tid >> 5;
        const int h0 = hb * 8;
        const int recv = (rg < 8) ? i0 : i1;
        const f16x8 fz = {};
        f16x8 u8 = *(const f16x8*)&Utab[rg >> 3][h0];
        const int j0 = (rg & 7) * 8;
        const f16x8* vrow = (const f16x8*)(Vp + (size_t)(b * NN + j0) * HH + h0);
        #pragma unroll
        for (int k = 0; k < 8; ++k) {
            int r = rg * 8 + k;
            f16x8 v8 = vrow[k * (HH / 8)];
            f16x8 hv = __builtin_elementwise_max(u8 + v8, fz);
            *(f16x8*)(h1 + r * 512 + (((hb ^ (r & 31)) & 31) << 4)) = hv;
        }
        // self edge: row r where sender j == recv (uniform branch, 1/8 of threads)
        if ((rg & 7) == (recv >> 3)) {
            int k = recv & 7;
            int r = rg * 8 + k;
            *(f16x8*)(h1 + r * 512 + (((hb ^ (r & 31)) & 31) << 4)) = fz;
        }
    }
    __syncthreads();

    // ---- layer 2: [128,256] @ [256,256] via 32x32x16; wave = 2mt x 2nt ----
    const int ln = lane & 31;     // col within ntile
    const int kh = lane >> 5;     // k-half selector
    const int wm = w >> 2;        // 0..1: mt pair (rows 64*wm..+63, recv i0/i1)
    const int wn = w & 3;         // 0..3: nt pair (cols 64*wn..+63)

    float b2v[2];
    #pragma unroll
    for (int nt = 0; nt < 2; ++nt) b2v[nt] = b2[(wn * 2 + nt) * 32 + ln];

    f32x16 acc[2][2];
    #pragma unroll
    for (int mt = 0; mt < 2; ++mt)
        #pragma unroll
        for (int nt = 0; nt < 2; ++nt)
            #pragma unroll
            for (int e = 0; e < 16; ++e) acc[mt][nt][e] = b2v[nt];

    #pragma unroll
    for (int ks = 0; ks < 16; ++ks) {
        f16x8 bb[2];
        #pragma unroll
        for (int nt = 0; nt < 2; ++nt)
            bb[nt] = *(const f16x8*)(W2p + (size_t)((ks * 8 + wn * 2 + nt) * 64 + lane) * 8);
        #pragma unroll
        for (int mt = 0; mt < 2; ++mt) {
            int row = wm * 64 + mt * 32 + ln;
            int c16 = (ks * 2 + kh) ^ (row & 31);
            f16x8 a = *(const f16x8*)(h1 + row * 512 + (c16 << 4));
            #pragma unroll
            for (int nt = 0; nt < 2; ++nt)
                acc[mt][nt] = __builtin_amdgcn_mfma_f32_32x32x16_f16(a, bb[nt], acc[mt][nt], 0, 0, 0);
        }
    }

    // ---- relu + row-sum over 64 rows (one receiver per wave) ----
    // C layout 32x32: col = lane&31, row = (e&3) + 8*(e>>2) + 4*(lane>>5)
    const int recv = (wm == 0) ? i0 : i1;
    float s[2] = {0.f, 0.f};
    #pragma unroll
    for (int mt = 0; mt < 2; ++mt)
        #pragma unroll
        for (int nt = 0; nt < 2; ++nt) {
            float t = 0.f;
            #pragma unroll
            for (int e = 0; e < 16; ++e) t += fmaxf(acc[mt][nt][e], 0.f);
            s[nt] += t;
        }
    #pragma unroll
    for (int nt = 0; nt < 2; ++nt) s[nt] += __shfl_xor(s[nt], 32);
    if (lane < 32) {
        #pragma unroll
        for (int nt = 0; nt < 2; ++nt) {
            int col = (wn * 2 + nt) * 32 + ln;
            innode[(size_t)(b * NN + recv) * 288 + col] =
                (f16_t)(s[nt] - fmaxf(b2v[nt], 0.f));
        }
    }
}

// ------------------------------------------------------------------
// Node MLP: [8192,288] -> relu 256 -> relu 256 -> 4.
// 512 blocks x 16 rows x 256 threads (4 waves; wave = 1mt x 4nt).
// Small LDS (~26 KB) -> 4+ blocks/CU for latency hiding.
// ------------------------------------------------------------------
__global__ __launch_bounds__(256, 4) void node_kernel(
    const f16_t* __restrict__ innode,  // [8192][288]
    const f16_t* __restrict__ W1op,
    const float* __restrict__ bo1,
    const f16_t* __restrict__ W2op,
    const float* __restrict__ bo2,
    const float* __restrict__ W3,      // [256][4] fp32
    const float* __restrict__ bo3,     // [4]
    float* __restrict__ out)           // [8192][4]
{
    __shared__ __align__(16) char bufA[16 * 640];
    __shared__ __align__(16) char bufB[16 * 512];
    __shared__ __align__(16) char bufC[16 * 528];

    const int tid  = threadIdx.x;
    const int lane = tid & 63;
    const int w    = tid >> 6;          // 0..3 = nt quad
    const int m0   = blockIdx.x * 16;
    const int lm   = lane & 15, lk = lane >> 4;

    for (int idx = tid; idx < 16 * 36; idx += 256) {
        int r = idx / 36, c = idx - r * 36;
        f16x8 v = *(const f16x8*)(innode + (size_t)(m0 + r) * 288 + c * 8);
        *(f16x8*)(bufA + ((r * 640 + c * 16) ^ ((r & 7) << 4))) = v;
    }
    __syncthreads();

    // ---- layer 1: K=288 (9 k-steps), bias in C-init ----
    f32x4 acc1[4];
    #pragma unroll
    for (int nt = 0; nt < 4; ++nt) {
        float bias = bo1[(w * 4 + nt) * 16 + lm];
        acc1[nt] = (f32x4){bias, bias, bias, bias};
    }
    #pragma unroll
    for (int ks = 0; ks < 9; ++ks) {
        f16x8 a = *(const f16x8*)(bufA + ((lm * 640 + ks * 64 + lk * 16) ^ ((lm & 7) << 4)));
        #pragma unroll
        for (int nt = 0; nt < 4; ++nt) {
            f16x8 bb = *(const f16x8*)(W1op + (size_t)((ks * 16 + w * 4 + nt) * 64 + lane) * 8);
            acc1[nt] = __builtin_amdgcn_mfma_f32_16x16x32_f16(a, bb, acc1[nt], 0, 0, 0);
        }
    }
    #pragma unroll
    for (int nt = 0; nt < 4; ++nt) {
        int col = (w * 4 + nt) * 16 + lm;
        #pragma unroll
        for (int j = 0; j < 4; ++j) {
            int row = lk * 4 + j;
            float v = fmaxf(acc1[nt][j], 0.f);
            *(f16_t*)(bufB + ((row * 512 + col * 2) ^ ((row & 7) << 4))) = (f16_t)v;
        }
    }
    __syncthreads();

    // ---- layer 2: K=256 (8 k-steps) ----
    f32x4 acc2[4];
    #pragma unroll
    for (int nt = 0; nt < 4; ++nt) {
        float bias = bo2[(w * 4 + nt) * 16 + lm];
        acc2[nt] = (f32x4){bias, bias, bias, bias};
    }
    #pragma unroll
    for (int ks = 0; ks < 8; ++ks) {
        f16x8 a = *(const f16x8*)(bufB + ((lm * 512 + ks * 64 + lk * 16) ^ ((lm & 7) << 4)));
        #pragma unroll
        for (int nt = 0; nt < 4; ++nt) {
            f16x8 bb = *(const f16x8*)(W2op + (size_t)((ks * 16 + w * 4 + nt) * 64 + lane) * 8);
            acc2[nt] = __builtin_amdgcn_mfma_f32_16x16x32_f16(a, bb, acc2[nt], 0, 0, 0);
        }
    }
    f16_t* c16 = (f16_t*)bufC;
    #pragma unroll
    for (int nt = 0; nt < 4; ++nt) {
        int col = (w * 4 + nt) * 16 + lm;
        #pragma unroll
        for (int j = 0; j < 4; ++j) {
            int row = lk * 4 + j;
            float v = fmaxf(acc2[nt][j], 0.f);
            c16[row * 264 + col] = (f16_t)v;
        }
    }
    __syncthreads();

    // ---- layer 3: [16,256] @ [256,4]; all 256 threads, 4-way k-split ----
    {
        int m = tid >> 4;          // 0..15
        int o = (tid >> 2) & 3;    // 0..3
        int q = tid & 3;           // k quarter
        const f16_t* crow = c16 + m * 264 + q * 64;
        float s = 0.f;
        int rot = (lane & 15) * 4; // rotate k to spread LDS banks
        #pragma unroll 8
        for (int k = 0; k < 64; ++k) {
            int kk = (k + rot) & 63;
            s += (float)crow[kk] * W3[(q * 64 + kk) * 4 + o];
        }
        s += __shfl_xor(s, 1);
        s += __shfl_xor(s, 2);
        if (q == 0) out[(size_t)(m0 + m) * 4 + o] = s + bo3[o];
    }
}

// ------------------------------------------------------------------
extern "C" void kernel_launch(void* const* d_in, const int* in_sizes, int n_in,
                              void* d_out, int out_size, void* d_ws, size_t ws_size,
                              hipStream_t stream)
{
    (void)in_sizes; (void)n_in; (void)out_size; (void)ws_size;
    const float* x      = (const float*)d_in[0];
    const float* W_msg1 = (const float*)d_in[4];
    const float* b_msg1 = (const float*)d_in[5];
    const float* W_msg2 = (const float*)d_in[6];
    const float* b_msg2 = (const float*)d_in[7];
    const float* W_out1 = (const float*)d_in[8];
    const float* b_out1 = (const float*)d_in[9];
    const float* W_out2 = (const float*)d_in[10];
    const float* b_out2 = (const float*)d_in[11];
    const float* W_out3 = (const float*)d_in[12];
    const float* b_out3 = (const float*)d_in[13];
    float* out = (float*)d_out;

    char* ws = (char*)d_ws;
    f16_t* W2p    = (f16_t*)(ws + 0);
    f16_t* W1op   = (f16_t*)(ws + 131072);
    f16_t* W2op   = (f16_t*)(ws + 278528);
    f16_t* innode = (f16_t*)(ws + 409600);
    f16_t* Vp     = (f16_t*)(ws + 5128192);

    prep_all<<<1124, 256, 0, stream>>>(x, W_msg1, W_msg2, W_out1, W_out2,
                                       W2p, W1op, W2op, Vp);
    edge_kernel<<<4096, 512, 0, stream>>>(x, W_msg1, b_msg1, Vp, W2p, b_msg2, innode);
    node_kernel<<<512, 256, 0, stream>>>(innode, W1op, b_out1, W2op, b_out2,
                                         W_out3, b_out3, out);
}

// Round 6
// 95.590 us; speedup vs baseline: 1.1094x; 1.1094x over previous
//
#include <hip/hip_runtime.h>
#include <cstddef>

typedef _Float16 f16_t;
typedef _Float16 f16x8 __attribute__((ext_vector_type(8)));
typedef float    f32x4  __attribute__((ext_vector_type(4)));
typedef float    f32x16 __attribute__((ext_vector_type(16)));

static constexpr int NN = 64;    // nodes
static constexpr int FF = 4;     // features
static constexpr int HH = 256;   // hidden

// ---- workspace layout (bytes) ----
// W2p    @ 0       : 131072   (W_msg2 packed 32x32x16 B-frags, f16)
// W1op   @ 131072  : 147456   (W_out1 padded/remapped 16x16x32, f16)
// W2op   @ 278528  : 131072   (W_out2 packed 16x16x32, f16)
// innode @ 409600  : 4718592  ([agg(256) | x(4) | pad(28)] f16, 8192 rows)
// Vp     @ 5128192 : 4194304  (V = x @ W1[4:8], f16 [128][64][256])

// ------------------------------------------------------------------
// 16x16x32 B-frag pack: lane holds B[k=ks*32+(lane>>4)*8+j][col=nt*16+(lane&15)]
// ------------------------------------------------------------------
__device__ inline void pack_frag16(const float* __restrict__ src, f16_t* __restrict__ dst,
                                   int fid, int ksteps, int mode)
{
    if (fid >= ksteps * 1024) return;
    int lane = fid & 63;
    int nt   = (fid >> 6) & 15;
    int ks   = fid >> 10;
    int col  = nt * 16 + (lane & 15);
    int kb   = ks * 32 + (lane >> 4) * 8;
    #pragma unroll
    for (int j = 0; j < 8; ++j) {
        int k = kb + j;
        float v;
        if (mode == 0) {
            v = src[k * 256 + col];
        } else {
            if (k < 256)      v = src[(4 + k) * 256 + col];
            else if (k < 260) v = src[(k - 256) * 256 + col];
            else              v = 0.f;
        }
        dst[(size_t)fid * 8 + j] = (f16_t)v;
    }
}

// ------------------------------------------------------------------
// 32x32x16 B-frag pack: lane holds B[k=ks*16+(lane>>5)*8+j][col=nt*32+(lane&31)]
// fid = (ks*8 + nt)*64 + lane, ks in [0,16), nt in [0,8)
// ------------------------------------------------------------------
__device__ inline void pack_frag32(const float* __restrict__ src, f16_t* __restrict__ dst,
                                   int fid)
{
    int lane = fid & 63;
    int nt   = (fid >> 6) & 7;
    int ks   = fid >> 9;
    int col  = nt * 32 + (lane & 31);
    int kb   = ks * 16 + (lane >> 5) * 8;
    #pragma unroll
    for (int j = 0; j < 8; ++j)
        dst[(size_t)fid * 8 + j] = (f16_t)src[(kb + j) * 256 + col];
}

// ------------------------------------------------------------------
// Fused prep: weight packs + V precompute.
// blocks [0,32): W2p(32x32)  [32,68): W1op  [68,100): W2op  [100,1124): Vp
// ------------------------------------------------------------------
__global__ void prep_all(const float* __restrict__ x,
                         const float* __restrict__ W_msg1,
                         const float* __restrict__ W_msg2,
                         const float* __restrict__ W_out1,
                         const float* __restrict__ W_out2,
                         f16_t* __restrict__ W2p, f16_t* __restrict__ W1op,
                         f16_t* __restrict__ W2op, f16_t* __restrict__ Vp)
{
    int bid = blockIdx.x, tid = threadIdx.x;
    if (bid < 32) {
        pack_frag32(W_msg2, W2p, bid * 256 + tid);
    } else if (bid < 68) {
        pack_frag16(W_out1, W1op, (bid - 32) * 256 + tid, 9, 1);
    } else if (bid < 100) {
        pack_frag16(W_out2, W2op, (bid - 68) * 256 + tid, 8, 0);
    } else {
        int gid  = (bid - 100) * 256 + tid;   // 262144
        int rown = gid >> 5;                   // b*64+n
        int h0   = (gid & 31) * 8;
        float4 xv = ((const float4*)x)[rown];
        f16x8 o;
        #pragma unroll
        for (int u = 0; u < 8; ++u) {
            float s = xv.x * W_msg1[4 * HH + h0 + u] + xv.y * W_msg1[5 * HH + h0 + u]
                    + xv.z * W_msg1[6 * HH + h0 + u] + xv.w * W_msg1[7 * HH + h0 + u];
            o[u] = (f16_t)s;
        }
        *(f16x8*)(Vp + (size_t)rown * HH + h0) = o;
    }
}

// ------------------------------------------------------------------
// Edge MLP + aggregation. One block = (batch b, receivers i0,i1).
// 256 threads = 4 waves; wave wn owns cols wn*64..+63 (2 ntiles) over
// ALL 128 rows (4 mtiles): per CU-round (2 blocks) A-LDS = 512 b128
// = 6.1K cyc, B-L2 = 256 KB = 4.7K cyc, MFMA = 8.2K cyc <- pole.
// (R4 was LDS-pole 12.3K at MT4NT1; R5 was L2-pole 9.4K at MT2NT2.)
// h1[r] = relu(U_recv + V_j), packed fp16; LDS [128][256] f16, 5-bit
// slot swizzle (PMC-verified 0 conflicts).
// Self rows zeroed in h1; agg corrected by subtracting relu(b2).
// ------------------------------------------------------------------
__global__ __launch_bounds__(256, 2) void edge_kernel(
    const float* __restrict__ x,      // [128][64][4]
    const float* __restrict__ W1,     // [8][256]
    const float* __restrict__ b1,     // [256]
    const f16_t* __restrict__ Vp,     // [128][64][256]
    const f16_t* __restrict__ W2p,    // packed 32x32
    const float* __restrict__ b2,     // [256]
    f16_t* __restrict__ innode)       // [8192][288]
{
    __shared__ __align__(16) char h1[128 * 512];   // 64 KiB f16, swizzled
    __shared__ __align__(16) f16_t Utab[2][256];

    const int tid  = threadIdx.x;
    const int lane = tid & 63;
    const int w    = tid >> 6;        // 0..3 = wn (col strip)
    const int b    = blockIdx.x >> 5;
    const int pr   = blockIdx.x & 31;
    const int i0   = pr * 2, i1 = i0 + 1;

    // ---- U table: 512 entries, 2 per thread ----
    #pragma unroll
    for (int i = 0; i < 2; ++i) {
        int e    = tid + i * 256;
        int rs   = e >> 8;                // 0 -> i0, 1 -> i1
        int h    = e & 255;
        int node = rs ? i1 : i0;
        const float* xr = x + (b * NN + node) * FF;
        float s = b1[h] + xr[0] * W1[h] + xr[1] * W1[HH + h]
                        + xr[2] * W1[2 * HH + h] + xr[3] * W1[3 * HH + h];
        Utab[rs][h] = (f16_t)s;
    }
    // x + zero-pad tail columns 256..287 of innode
    if (tid < 64) {
        int node = (tid < 32) ? i0 : i1;
        int c = tid & 31;
        float v = (c < 4) ? x[(b * NN + node) * FF + c] : 0.f;
        innode[(size_t)(b * NN + node) * 288 + 256 + c] = (f16_t)v;
    }
    __syncthreads();

    // ---- h1: thread = (row-group rg 0..7, 16 rows) x (8-col block hb) ----
    {
        const int hb = tid & 31;
        const int rg = tid >> 5;
        const int h0 = hb * 8;
        const int recv = (rg < 4) ? i0 : i1;
        const f16x8 fz = {};
        f16x8 u8 = *(const f16x8*)&Utab[rg >> 2][h0];
        const int j0 = (rg & 3) * 16;
        const f16x8* vrow = (const f16x8*)(Vp + (size_t)(b * NN + j0) * HH + h0);
        #pragma unroll
        for (int k = 0; k < 16; ++k) {
            int r = rg * 16 + k;          // j = j0 + k = r & 63
            f16x8 v8 = vrow[k * (HH / 8)];
            f16x8 hv = __builtin_elementwise_max(u8 + v8, fz);
            *(f16x8*)(h1 + r * 512 + (((hb ^ (r & 31)) & 31) << 4)) = hv;
        }
        // self edge: row where sender j == recv (uniform branch, 1/4 of threads)
        if ((rg & 3) == (recv >> 4)) {
            int r = rg * 16 + (recv & 15);
            *(f16x8*)(h1 + r * 512 + (((hb ^ (r & 31)) & 31) << 4)) = fz;
        }
    }
    __syncthreads();

    // ---- layer 2: [128,256] @ [256,256] via 32x32x16; wave = 4mt x 2nt ----
    const int ln = lane & 31;     // col within ntile
    const int kh = lane >> 5;     // k-half selector
    const int wn = w;             // col strip: cols wn*64 .. +63

    float b2v[2];
    #pragma unroll
    for (int nt = 0; nt < 2; ++nt) b2v[nt] = b2[(wn * 2 + nt) * 32 + ln];

    f32x16 acc[4][2];
    #pragma unroll
    for (int mt = 0; mt < 4; ++mt)
        #pragma unroll
        for (int nt = 0; nt < 2; ++nt)
            #pragma unroll
            for (int e = 0; e < 16; ++e) acc[mt][nt][e] = b2v[nt];

    #pragma unroll
    for (int ks = 0; ks < 16; ++ks) {
        f16x8 bb[2];
        #pragma unroll
        for (int nt = 0; nt < 2; ++nt)
            bb[nt] = *(const f16x8*)(W2p + (size_t)((ks * 8 + wn * 2 + nt) * 64 + lane) * 8);
        #pragma unroll
        for (int mt = 0; mt < 4; ++mt) {
            int row = mt * 32 + ln;
            int c16 = (ks * 2 + kh) ^ (row & 31);
            f16x8 a = *(const f16x8*)(h1 + row * 512 + (c16 << 4));
            #pragma unroll
            for (int nt = 0; nt < 2; ++nt)
                acc[mt][nt] = __builtin_amdgcn_mfma_f32_32x32x16_f16(a, bb[nt], acc[mt][nt], 0, 0, 0);
        }
    }

    // ---- relu + row-sum; rows 0..63 -> i0 (mt 0,1), 64..127 -> i1 (mt 2,3) ----
    // C layout 32x32: col = lane&31, row = (e&3) + 8*(e>>2) + 4*(lane>>5)
    float s0[2] = {0.f, 0.f}, s1[2] = {0.f, 0.f};
    #pragma unroll
    for (int mt = 0; mt < 4; ++mt)
        #pragma unroll
        for (int nt = 0; nt < 2; ++nt) {
            float t = 0.f;
            #pragma unroll
            for (int e = 0; e < 16; ++e) t += fmaxf(acc[mt][nt][e], 0.f);
            if (mt < 2) s0[nt] += t; else s1[nt] += t;
        }
    #pragma unroll
    for (int nt = 0; nt < 2; ++nt) {
        s0[nt] += __shfl_xor(s0[nt], 32);
        s1[nt] += __shfl_xor(s1[nt], 32);
    }
    if (lane < 32) {
        #pragma unroll
        for (int nt = 0; nt < 2; ++nt) {
            float sub = fmaxf(b2v[nt], 0.f);
            int col = (wn * 2 + nt) * 32 + ln;
            innode[(size_t)(b * NN + i0) * 288 + col] = (f16_t)(s0[nt] - sub);
            innode[(size_t)(b * NN + i1) * 288 + col] = (f16_t)(s1[nt] - sub);
        }
    }
}

// ------------------------------------------------------------------
// Node MLP: [8192,288] -> relu 256 -> relu 256 -> 4.
// 512 blocks x 16 rows x 256 threads (4 waves; wave = 1mt x 4nt).
// ------------------------------------------------------------------
__global__ __launch_bounds__(256, 4) void node_kernel(
    const f16_t* __restrict__ innode,  // [8192][288]
    const f16_t* __restrict__ W1op,
    const float* __restrict__ bo1,
    const f16_t* __restrict__ W2op,
    const float* __restrict__ bo2,
    const float* __restrict__ W3,      // [256][4] fp32
    const float* __restrict__ bo3,     // [4]
    float* __restrict__ out)           // [8192][4]
{
    __shared__ __align__(16) char bufA[16 * 640];
    __shared__ __align__(16) char bufB[16 * 512];
    __shared__ __align__(16) char bufC[16 * 528];

    const int tid  = threadIdx.x;
    const int lane = tid & 63;
    const int w    = tid >> 6;          // 0..3 = nt quad
    const int m0   = blockIdx.x * 16;
    const int lm   = lane & 15, lk = lane >> 4;

    for (int idx = tid; idx < 16 * 36; idx += 256) {
        int r = idx / 36, c = idx - r * 36;
        f16x8 v = *(const f16x8*)(innode + (size_t)(m0 + r) * 288 + c * 8);
        *(f16x8*)(bufA + ((r * 640 + c * 16) ^ ((r & 7) << 4))) = v;
    }
    __syncthreads();

    // ---- layer 1: K=288 (9 k-steps), bias in C-init ----
    f32x4 acc1[4];
    #pragma unroll
    for (int nt = 0; nt < 4; ++nt) {
        float bias = bo1[(w * 4 + nt) * 16 + lm];
        acc1[nt] = (f32x4){bias, bias, bias, bias};
    }
    #pragma unroll
    for (int ks = 0; ks < 9; ++ks) {
        f16x8 a = *(const f16x8*)(bufA + ((lm * 640 + ks * 64 + lk * 16) ^ ((lm & 7) << 4)));
        #pragma unroll
        for (int nt = 0; nt < 4; ++nt) {
            f16x8 bb = *(const f16x8*)(W1op + (size_t)((ks * 16 + w * 4 + nt) * 64 + lane) * 8);
            acc1[nt] = __builtin_amdgcn_mfma_f32_16x16x32_f16(a, bb, acc1[nt], 0, 0, 0);
        }
    }
    #pragma unroll
    for (int nt = 0; nt < 4; ++nt) {
        int col = (w * 4 + nt) * 16 + lm;
        #pragma unroll
        for (int j = 0; j < 4; ++j) {
            int row = lk * 4 + j;
            float v = fmaxf(acc1[nt][j], 0.f);
            *(f16_t*)(bufB + ((row * 512 + col * 2) ^ ((row & 7) << 4))) = (f16_t)v;
        }
    }
    __syncthreads();

    // ---- layer 2: K=256 (8 k-steps) ----
    f32x4 acc2[4];
    #pragma unroll
    for (int nt = 0; nt < 4; ++nt) {
        float bias = bo2[(w * 4 + nt) * 16 + lm];
        acc2[nt] = (f32x4){bias, bias, bias, bias};
    }
    #pragma unroll
    for (int ks = 0; ks < 8; ++ks) {
        f16x8 a = *(const f16x8*)(bufB + ((lm * 512 + ks * 64 + lk * 16) ^ ((lm & 7) << 4)));
        #pragma unroll
        for (int nt = 0; nt < 4; ++nt) {
            f16x8 bb = *(const f16x8*)(W2op + (size_t)((ks * 16 + w * 4 + nt) * 64 + lane) * 8);
            acc2[nt] = __builtin_amdgcn_mfma_f32_16x16x32_f16(a, bb, acc2[nt], 0, 0, 0);
        }
    }
    f16_t* c16 = (f16_t*)bufC;
    #pragma unroll
    for (int nt = 0; nt < 4; ++nt) {
        int col = (w * 4 + nt) * 16 + lm;
        #pragma unroll
        for (int j = 0; j < 4; ++j) {
            int row = lk * 4 + j;
            float v = fmaxf(acc2[nt][j], 0.f);
            c16[row * 264 + col] = (f16_t)v;
        }
    }
    __syncthreads();

    // ---- layer 3: [16,256] @ [256,4]; all 256 threads, 4-way k-split ----
    {
        int m = tid >> 4;          // 0..15
        int o = (tid >> 2) & 3;    // 0..3
        int q = tid & 3;           // k quarter
        const f16_t* crow = c16 + m * 264 + q * 64;
        float s = 0.f;
        int rot = (lane & 15) * 4; // rotate k to spread LDS banks
        #pragma unroll 8
        for (int k = 0; k < 64; ++k) {
            int kk = (k + rot) & 63;
            s += (float)crow[kk] * W3[(q * 64 + kk) * 4 + o];
        }
        s += __shfl_xor(s, 1);
        s += __shfl_xor(s, 2);
        if (q == 0) out[(size_t)(m0 + m) * 4 + o] = s + bo3[o];
    }
}

// ------------------------------------------------------------------
extern "C" void kernel_launch(void* const* d_in, const int* in_sizes, int n_in,
                              void* d_out, int out_size, void* d_ws, size_t ws_size,
                              hipStream_t stream)
{
    (void)in_sizes; (void)n_in; (void)out_size; (void)ws_size;
    const float* x      = (const float*)d_in[0];
    const float* W_msg1 = (const float*)d_in[4];
    const float* b_msg1 = (const float*)d_in[5];
    const float* W_msg2 = (const float*)d_in[6];
    const float* b_msg2 = (const float*)d_in[7];
    const float* W_out1 = (const float*)d_in[8];
    const float* b_out1 = (const float*)d_in[9];
    const float* W_out2 = (const float*)d_in[10];
    const float* b_out2 = (const float*)d_in[11];
    const float* W_out3 = (const float*)d_in[12];
    const float* b_out3 = (const float*)d_in[13];
    float* out = (float*)d_out;

    char* ws = (char*)d_ws;
    f16_t* W2p    = (f16_t*)(ws + 0);
    f16_t* W1op   = (f16_t*)(ws + 131072);
    f16_t* W2op   = (f16_t*)(ws + 278528);
    f16_t* innode = (f16_t*)(ws + 409600);
    f16_t* Vp     = (f16_t*)(ws + 5128192);

    prep_all<<<1124, 256, 0, stream>>>(x, W_msg1, W_msg2, W_out1, W_out2,
                                       W2p, W1op, W2op, Vp);
    edge_kernel<<<4096, 256, 0, stream>>>(x, W_msg1, b_msg1, Vp, W2p, b_msg2, innode);
    node_kernel<<<512, 256, 0, stream>>>(innode, W1op, b_out1, W2op, b_out2,
                                         W_out3, b_out3, out);
}